// Round 3
// baseline (87.177 us; speedup 1.0000x reference)
//
#include <hip/hip_runtime.h>

// CrossAttention MI355X — round 6: barrier-free attention, K/V direct from L2.
// K+V per (b,h) = 128KB, all slices 2MB total -> fully L2-resident. Drop LDS
// staging entirely: each wave loads its MFMA fragments straight from global
// (same gather pattern), register double-buffered across 128-key chunks.
// No __syncthreads, no vmcnt(0) drains, waves fully independent.
// B=2, C=256, H=W=64 -> N=4096 q-tokens; kv pooled -> Nk=1024. HEADS=8, HDIM=32.

#define CDIM   256
#define NTOK   4096
#define NKTOK  1024
#define HDIM   32
// ATTN_SCALE * log2(e): exp(x*s) = 2^(x*s*log2e); fold into Q projection.
#define QSCALE 0.2550530290582177f
#define LN_EPS 1e-5f

typedef __attribute__((ext_vector_type(8))) short bf16x8;
typedef __attribute__((ext_vector_type(4))) float f32x4;
typedef __attribute__((ext_vector_type(4))) uint u32x4;

__device__ __forceinline__ ushort f2bf(float f) {
  uint u = __builtin_bit_cast(uint, f);
  u += 0x7fff + ((u >> 16) & 1);
  return (ushort)(u >> 16);
}

__device__ __forceinline__ float fast_exp2(float x) {
  float r;
  asm("v_exp_f32 %0, %1" : "=v"(r) : "v"(x));
  return r;
}

__device__ __forceinline__ uint cvt_pk_bf16(float lo, float hi) {
  uint r;
  asm("v_cvt_pk_bf16_f32 %0, %1, %2" : "=v"(r) : "v"(lo), "v"(hi));
  return r;
}

// ================= prep: wconv (blocks 0..255) | ln_q (256..767) | pool_ln (768..1023) =================
__global__ __launch_bounds__(256) void prep_kernel(
    const float* __restrict__ q_feat, const float* __restrict__ kv_feat,
    const float* __restrict__ nqw, const float* __restrict__ nqb,
    const float* __restrict__ nkw, const float* __restrict__ nkb,
    const float* __restrict__ wq, const float* __restrict__ wk,
    const float* __restrict__ wvv, const float* __restrict__ wp,
    ushort* __restrict__ wq_bf, ushort* __restrict__ wk_bf,
    ushort* __restrict__ wv_bf, ushort* __restrict__ wp_bf,
    ushort* __restrict__ q_ln, ushort* __restrict__ kv_ln) {
  __shared__ float preds[2][256];
  __shared__ float pstat[2][32];
  const int bid = blockIdx.x;
  const int tid = threadIdx.x;

  if (bid < 256) {
    // ---- weight fp32 -> bf16 ----
    const int mat = bid >> 6;
    const int base = (bid & 63) * 1024 + tid * 4;
    const float* s; ushort* d;
    switch (mat) {
      case 0: s = wq; d = wq_bf; break;
      case 1: s = wk; d = wk_bf; break;
      case 2: s = wvv; d = wv_bf; break;
      default: s = wp; d = wp_bf; break;
    }
    const float4 v = *reinterpret_cast<const float4*>(s + base);
    uint2 pk;
    pk.x = (uint)f2bf(v.x) | ((uint)f2bf(v.y) << 16);
    pk.y = (uint)f2bf(v.z) | ((uint)f2bf(v.w) << 16);
    *reinterpret_cast<uint2*>(d + base) = pk;
    return;
  }

  if (bid < 768) {
    // ---- LN q: 16 tokens/block, thread = (cg = tid>>4 of 16 ch, tok = tid&15) ----
    const int tok = tid & 15, cg = tid >> 4;
    const int T = (bid - 256) * 16 + tok;         // b*4096 + n
    const int b = T >> 12, n = T & 4095;
    const float* src = q_feat + ((size_t)b * CDIM + cg * 16) * NTOK + n;
    float vals[16];
    float s = 0.f, ss = 0.f;
#pragma unroll
    for (int ci = 0; ci < 16; ++ci) {
      const float v = src[(size_t)ci * NTOK];
      vals[ci] = v;
      s += v; ss = fmaf(v, v, ss);
    }
    preds[0][cg * 16 + tok] = s;
    preds[1][cg * 16 + tok] = ss;
    __syncthreads();
    if (tid < 16) {
      float st = 0.f, sst = 0.f;
#pragma unroll
      for (int k = 0; k < 16; ++k) { st += preds[0][k * 16 + tid]; sst += preds[1][k * 16 + tid]; }
      const float mu = st * (1.f / 256.f);
      const float var = sst * (1.f / 256.f) - mu * mu;
      pstat[0][tid] = mu;
      pstat[1][tid] = rsqrtf(var + LN_EPS);
    }
    __syncthreads();
    const float mu = pstat[0][tok];
    const float rs = pstat[1][tok];
    ushort* dst = q_ln + (size_t)T * CDIM + cg * 16;
#pragma unroll
    for (int ci = 0; ci < 16; ci += 4) {
      ushort h[4];
#pragma unroll
      for (int j = 0; j < 4; ++j) {
        const int c = cg * 16 + ci + j;
        h[j] = f2bf(fmaf((vals[ci + j] - mu) * rs, nqw[c], nqb[c]));
      }
      uint2 pk;
      pk.x = (uint)h[0] | ((uint)h[1] << 16);
      pk.y = (uint)h[2] | ((uint)h[3] << 16);
      *reinterpret_cast<uint2*>(dst + ci) = pk;
    }
    return;
  }

  // ---- pool+LN kv: 8 tokens/block, thread = (cg = tid>>3 of 8 ch, tok = tid&7) ----
  {
    const int tok = tid & 7, cg = tid >> 3;
    const int T = (bid - 768) * 8 + tok;          // b*1024 + nk
    const int b = T >> 10, nk = T & 1023;
    const int hk = nk >> 5, wk2 = nk & 31;
    const float* src = kv_feat + ((size_t)b * CDIM + cg * 8) * NTOK + hk * 128 + wk2 * 2;
    float vals[8];
    float s = 0.f, ss = 0.f;
#pragma unroll
    for (int ci = 0; ci < 8; ++ci) {
      const float* p = src + (size_t)ci * NTOK;
      const float2 r0 = *reinterpret_cast<const float2*>(p);
      const float2 r1 = *reinterpret_cast<const float2*>(p + 64);
      const float v = 0.25f * ((r0.x + r0.y) + (r1.x + r1.y));
      vals[ci] = v;
      s += v; ss = fmaf(v, v, ss);
    }
    preds[0][cg * 8 + tok] = s;
    preds[1][cg * 8 + tok] = ss;
    __syncthreads();
    if (tid < 8) {
      float st = 0.f, sst = 0.f;
#pragma unroll
      for (int k = 0; k < 32; ++k) { st += preds[0][k * 8 + tid]; sst += preds[1][k * 8 + tid]; }
      const float mu = st * (1.f / 256.f);
      const float var = sst * (1.f / 256.f) - mu * mu;
      pstat[0][tid] = mu;
      pstat[1][tid] = rsqrtf(var + LN_EPS);
    }
    __syncthreads();
    const float mu = pstat[0][tok];
    const float rs = pstat[1][tok];
    ushort* dst = kv_ln + (size_t)T * CDIM + cg * 8;
#pragma unroll
    for (int ci = 0; ci < 8; ci += 4) {
      ushort h[4];
#pragma unroll
      for (int j = 0; j < 4; ++j) {
        const int c = cg * 8 + ci + j;
        h[j] = f2bf(fmaf((vals[ci + j] - mu) * rs, nkw[c], nkb[c]));
      }
      uint2 pk;
      pk.x = (uint)h[0] | ((uint)h[1] << 16);
      pk.y = (uint)h[2] | ((uint)h[3] << 16);
      *reinterpret_cast<uint2*>(dst + ci) = pk;
    }
  }
}

// ================= fused QKV projection =================
// blocks: [0,256) Q (M=8192), [256,320) K (M=2048), [320,384) V (M=2048).
// block = 4 waves; wave = 16 rows x 128 cols (rowgrp = wv>>1, colhalf = wv&1).
__global__ __launch_bounds__(256) void qkv_kernel(
    const ushort* __restrict__ q_ln, const ushort* __restrict__ kv_ln,
    const ushort* __restrict__ wq_bf, const ushort* __restrict__ wk_bf,
    const ushort* __restrict__ wv_bf,
    const float* __restrict__ bq, const float* __restrict__ bk,
    const float* __restrict__ bv,
    ushort* __restrict__ Qp, ushort* __restrict__ Kp, ushort* __restrict__ Vt) {
  const int bid = blockIdx.x;
  int seg, sb;
  const ushort *X, *W; const float* bias;
  if (bid < 256)      { seg = 0; sb = bid;       X = q_ln;  W = wq_bf; bias = bq; }
  else if (bid < 320) { seg = 1; sb = bid - 256; X = kv_ln; W = wk_bf; bias = bk; }
  else                { seg = 2; sb = bid - 320; X = kv_ln; W = wv_bf; bias = bv; }

  const int lane = threadIdx.x & 63;
  const int wvi = threadIdx.x >> 6;
  const int nlan = lane & 15, g = lane >> 4;
  const int rowgrp = wvi >> 1, colh = wvi & 1;
  const int r0 = sb * 32 + rowgrp * 16;

  f32x4 acc[8];
#pragma unroll
  for (int nt = 0; nt < 8; ++nt) acc[nt] = (f32x4){0.f, 0.f, 0.f, 0.f};

  const ushort* xp = X + (size_t)(r0 + nlan) * CDIM + g * 8;
  const ushort* wp = W + (size_t)(colh * 128 + nlan) * CDIM + g * 8;
#pragma unroll
  for (int k0 = 0; k0 < 8; ++k0) {
    const bf16x8 a = *reinterpret_cast<const bf16x8*>(xp + k0 * 32);
#pragma unroll
    for (int nt = 0; nt < 8; ++nt) {
      const bf16x8 bfr = *reinterpret_cast<const bf16x8*>(wp + (size_t)nt * 16 * CDIM + k0 * 32);
      acc[nt] = __builtin_amdgcn_mfma_f32_16x16x32_bf16(a, bfr, acc[nt], 0, 0, 0);
    }
  }

#pragma unroll
  for (int nt = 0; nt < 8; ++nt) {
    const int j = colh * 128 + nt * 16 + nlan;
    const float bj = bias[j];
#pragma unroll
    for (int reg = 0; reg < 4; ++reg) {
      const int r = r0 + 4 * g + reg;
      const float v = acc[nt][reg] + bj;
      if (seg == 0) {
        Qp[(size_t)r * CDIM + j] = f2bf(v * QSCALE);
      } else if (seg == 1) {
        Kp[(size_t)r * CDIM + j] = f2bf(v);
      } else {
        const int h = j >> 5, d = j & 31;
        const int bb = r >> 10, m = r & 1023;
        Vt[((size_t)((bb * 8 + h) * 32 + d)) * NKTOK + m] = f2bf(v);
      }
    }
  }
}

// ================= attention =================
// grid (32, 16): x = 128-query tile (4 waves x 32 q), y = b*8+h. 256 threads.
// No LDS, no barriers. K/V (2MB total, L2-resident) are loaded per-wave
// straight into MFMA fragments, register double-buffered across 128-key chunks.
//   K-fragment t (t=0..7): lane (nlan,g) holds key kc+32*(t>>1)+8*(nlan>>2)
//     +4*(t&1)+(nlan&3), dims g*8..g*8+7 — so the swapped-QK^T outputs of
//     tiles 2m/2m+1 give this lane keys 32m+8g+{0..7} -> exp2 + 4x cvt_pk
//     build EXACTLY the 16x16x32 A-fragment P[q=nlan][k=8g+j] for PV.
//   V-fragment j (dt=j>>2, ks=j&3): lane (nlan,g) holds Vt[dt*16+nlan]
//     [kc+ks*32+8g..+7] — the PV B-operand.
__global__ __launch_bounds__(256) void attn_kernel(const ushort* __restrict__ Qp,
                                                   const ushort* __restrict__ Kp,
                                                   const ushort* __restrict__ Vt,
                                                   ushort* __restrict__ aout) {
  const int lane = threadIdx.x & 63;
  const int wvi = threadIdx.x >> 6;         // 0..3
  const int nlan = lane & 15, g = lane >> 4;
  const int bh = blockIdx.y;
  const int b = bh >> 3, h = bh & 7;
  const int n0 = blockIdx.x * 128 + wvi * 32;

  bf16x8 qf[2];
#pragma unroll
  for (int qt = 0; qt < 2; ++qt)
    qf[qt] = *reinterpret_cast<const bf16x8*>(
        Qp + (size_t)(b * NTOK + n0 + qt * 16 + nlan) * CDIM + h * HDIM + g * 8);

  // per-lane fragment base pointers (chunk offset added per load)
  const ushort* kfb = Kp + (size_t)b * NKTOK * CDIM + h * HDIM +
                      (size_t)((nlan >> 2) * 8 + (nlan & 3)) * CDIM + g * 8;
  const ushort* vfb = Vt + (size_t)(b * 8 + h) * HDIM * NKTOK +
                      (size_t)nlan * NKTOK + g * 8;

  f32x4 acc[2][2];
#pragma unroll
  for (int qt = 0; qt < 2; ++qt) {
    acc[qt][0] = (f32x4){0.f, 0.f, 0.f, 0.f};
    acc[qt][1] = (f32x4){0.f, 0.f, 0.f, 0.f};
  }
  float lsum[2] = {0.f, 0.f};
  const f32x4 zero = {0.f, 0.f, 0.f, 0.f};

  auto load_chunk = [&](bf16x8 (&KR)[8], bf16x8 (&VR)[8], int kc) {
#pragma unroll
    for (int t = 0; t < 8; ++t)
      KR[t] = *reinterpret_cast<const bf16x8*>(
          kfb + (size_t)(kc + (t >> 1) * 32 + (t & 1) * 4) * CDIM);
#pragma unroll
    for (int j = 0; j < 8; ++j)
      VR[j] = *reinterpret_cast<const bf16x8*>(
          vfb + (size_t)(j >> 2) * 16 * NKTOK + kc + (j & 3) * 32);
  };

  auto compute_chunk = [&](const bf16x8 (&KR)[8], const bf16x8 (&VR)[8]) {
#pragma unroll
    for (int m = 0; m < 4; ++m) {       // 32-key block
      uint pk[2][4];                    // [qt][4 packed uints = keys 8g+0..7]
#pragma unroll
      for (int half = 0; half < 2; ++half) {
        const bf16x8 kf = KR[2 * m + half];
#pragma unroll
        for (int qt = 0; qt < 2; ++qt) {
          const f32x4 s = __builtin_amdgcn_mfma_f32_16x16x32_bf16(kf, qf[qt], zero, 0, 0, 0);
          const float p0 = fast_exp2(s[0]), p1 = fast_exp2(s[1]);
          const float p2 = fast_exp2(s[2]), p3 = fast_exp2(s[3]);
          lsum[qt] += (p0 + p1) + (p2 + p3);
          pk[qt][half * 2 + 0] = cvt_pk_bf16(p0, p1);
          pk[qt][half * 2 + 1] = cvt_pk_bf16(p2, p3);
        }
      }
#pragma unroll
      for (int qt = 0; qt < 2; ++qt) {
        const u32x4 w = {pk[qt][0], pk[qt][1], pk[qt][2], pk[qt][3]};
        const bf16x8 af = __builtin_bit_cast(bf16x8, w);
#pragma unroll
        for (int dt = 0; dt < 2; ++dt)
          acc[qt][dt] = __builtin_amdgcn_mfma_f32_16x16x32_bf16(af, VR[dt * 4 + m], acc[qt][dt], 0, 0, 0);
      }
    }
  };

  bf16x8 KA[8], VA[8], KB[8], VB[8];
  load_chunk(KA, VA, 0);
#pragma unroll
  for (int c = 0; c < 8; c += 2) {
    load_chunk(KB, VB, (c + 1) * 128);
    compute_chunk(KA, VA);
    if (c + 2 < 8) load_chunk(KA, VA, (c + 2) * 128);
    compute_chunk(KB, VB);
  }

  // lsum per lane covers q = nlan, keys {8g..8g+7} over all blocks; reduce over g.
#pragma unroll
  for (int qt = 0; qt < 2; ++qt) {
    lsum[qt] += __shfl_xor(lsum[qt], 16);
    lsum[qt] += __shfl_xor(lsum[qt], 32);
  }

  ushort* dst = aout + (size_t)(b * NTOK + n0) * CDIM + h * HDIM;
#pragma unroll
  for (int qt = 0; qt < 2; ++qt) {
#pragma unroll
    for (int reg = 0; reg < 4; ++reg) {
      // acc row = q-row 4g+reg; its denominator lives at lane 4g+reg (nlan match).
      const float inv = 1.f / __shfl(lsum[qt], 4 * g + reg);
      const size_t row = (size_t)(qt * 16 + 4 * g + reg) * CDIM;
      dst[row + nlan] = f2bf(acc[qt][0][reg] * inv);
      dst[row + 16 + nlan] = f2bf(acc[qt][1][reg] * inv);
    }
  }
}

// ================= out projection + NCHW transpose =================
// 256 blocks x 32 tokens; wave = 16 rows x 128 cols; fp32 out (B,C,N).
__global__ __launch_bounds__(256) void outproj_kernel(const ushort* __restrict__ A,
                                                      const ushort* __restrict__ W,
                                                      const float* __restrict__ bias,
                                                      float* __restrict__ out) {
  __shared__ float ts[256][33];
  const int lane = threadIdx.x & 63;
  const int wvi = threadIdx.x >> 6;
  const int nlan = lane & 15, g = lane >> 4;
  const int rowgrp = wvi >> 1, colh = wvi & 1;
  const int r0b = blockIdx.x * 32;
  const int r0 = r0b + rowgrp * 16;

  f32x4 acc[8];
#pragma unroll
  for (int nt = 0; nt < 8; ++nt) acc[nt] = (f32x4){0.f, 0.f, 0.f, 0.f};

  const ushort* xp = A + (size_t)(r0 + nlan) * CDIM + g * 8;
  const ushort* wp = W + (size_t)(colh * 128 + nlan) * CDIM + g * 8;
#pragma unroll
  for (int k0 = 0; k0 < 8; ++k0) {
    const bf16x8 a = *reinterpret_cast<const bf16x8*>(xp + k0 * 32);
#pragma unroll
    for (int nt = 0; nt < 8; ++nt) {
      const bf16x8 bfr = *reinterpret_cast<const bf16x8*>(wp + (size_t)nt * 16 * CDIM + k0 * 32);
      acc[nt] = __builtin_amdgcn_mfma_f32_16x16x32_bf16(a, bfr, acc[nt], 0, 0, 0);
    }
  }

#pragma unroll
  for (int nt = 0; nt < 8; ++nt) {
    const int j = colh * 128 + nt * 16 + nlan;
    const float bj = bias[j];
#pragma unroll
    for (int reg = 0; reg < 4; ++reg)
      ts[j][rowgrp * 16 + 4 * g + reg] = acc[nt][reg] + bj;
  }
  __syncthreads();
  const int b = r0b >> 12;
  const int n0g = r0b & 4095;
#pragma unroll
  for (int k = 0; k < 32; ++k) {
    const int idx = k * 256 + threadIdx.x;
    const int cl = idx >> 5, tok = idx & 31;
    out[((size_t)b * CDIM + cl) * NTOK + n0g + tok] = ts[cl][tok];
  }
}

extern "C" void kernel_launch(void* const* d_in, const int* in_sizes, int n_in,
                              void* d_out, int out_size, void* d_ws, size_t ws_size,
                              hipStream_t stream) {
  (void)in_sizes; (void)n_in; (void)out_size; (void)ws_size;
  const float* q_feat  = (const float*)d_in[0];
  const float* kv_feat = (const float*)d_in[1];
  const float* nqw = (const float*)d_in[2];
  const float* nqb = (const float*)d_in[3];
  const float* nkw = (const float*)d_in[4];
  const float* nkb = (const float*)d_in[5];
  const float* wq  = (const float*)d_in[6];
  const float* bq  = (const float*)d_in[7];
  const float* wk  = (const float*)d_in[8];
  const float* bk  = (const float*)d_in[9];
  const float* wv  = (const float*)d_in[10];
  const float* bv  = (const float*)d_in[11];
  const float* wp  = (const float*)d_in[12];
  const float* bp  = (const float*)d_in[13];
  float* out = (float*)d_out;

  ushort* p = (ushort*)d_ws;
  ushort* wq_bf = p; p += 65536;
  ushort* wk_bf = p; p += 65536;
  ushort* wv_bf = p; p += 65536;
  ushort* wp_bf = p; p += 65536;
  ushort* q_ln  = p; p += 8192 * 256;
  ushort* kv_ln = p; p += 2048 * 256;
  ushort* Qp    = p; p += 8192 * 256;
  ushort* Kp    = p; p += 2048 * 256;
  ushort* Vt    = p; p += 2048 * 256;
  ushort* aout  = p; p += 8192 * 256;

  prep_kernel<<<1024, 256, 0, stream>>>(q_feat, kv_feat, nqw, nqb, nkw, nkb,
                                        wq, wk, wv, wp,
                                        wq_bf, wk_bf, wv_bf, wp_bf, q_ln, kv_ln);
  qkv_kernel<<<384, 256, 0, stream>>>(q_ln, kv_ln, wq_bf, wk_bf, wv_bf,
                                      bq, bk, bv, Qp, Kp, Vt);
  attn_kernel<<<dim3(32, 16), 256, 0, stream>>>(Qp, Kp, Vt, aout);
  outproj_kernel<<<256, 256, 0, stream>>>(aout, wp_bf, bp, out);
}

// Round 4
// 62.158 us; speedup vs baseline: 1.4025x; 1.4025x over previous
//
#include <hip/hip_runtime.h>

// CrossAttention MI355X — round 7: round-5 structure + PRE-TILED K/V pack.
// qkv writes K/V directly in the attention fragment-tile layout, so attn's
// global_load_lds staging is 16KB fully-CONTIGUOUS per chunk (was 256
// scattered 64B segments -> L3-latency bound). Compute identical to round 5.
// B=2, C=256, H=W=64 -> N=4096 q-tokens; kv pooled -> Nk=1024. HEADS=8, HDIM=32.

#define CDIM   256
#define NTOK   4096
#define NKTOK  1024
#define HDIM   32
// ATTN_SCALE * log2(e): exp(x*s) = 2^(x*s*log2e); fold into Q projection.
#define QSCALE 0.2550530290582177f
#define LN_EPS 1e-5f

typedef __attribute__((ext_vector_type(8))) short bf16x8;
typedef __attribute__((ext_vector_type(4))) float f32x4;
typedef __attribute__((ext_vector_type(4))) uint u32x4;

__device__ __forceinline__ ushort f2bf(float f) {
  uint u = __builtin_bit_cast(uint, f);
  u += 0x7fff + ((u >> 16) & 1);
  return (ushort)(u >> 16);
}

__device__ __forceinline__ float fast_exp2(float x) {
  float r;
  asm("v_exp_f32 %0, %1" : "=v"(r) : "v"(x));
  return r;
}

__device__ __forceinline__ uint cvt_pk_bf16(float lo, float hi) {
  uint r;
  asm("v_cvt_pk_bf16_f32 %0, %1, %2" : "=v"(r) : "v"(lo), "v"(hi));
  return r;
}

__device__ __forceinline__ void gload_lds16(const void* g, void* l) {
  __builtin_amdgcn_global_load_lds(
      (const __attribute__((address_space(1))) unsigned int*)g,
      (__attribute__((address_space(3))) unsigned int*)l, 16, 0, 0);
}

// ================= prep: wconv (blocks 0..255) | ln_q (256..767) | pool_ln (768..1023) =================
__global__ __launch_bounds__(256) void prep_kernel(
    const float* __restrict__ q_feat, const float* __restrict__ kv_feat,
    const float* __restrict__ nqw, const float* __restrict__ nqb,
    const float* __restrict__ nkw, const float* __restrict__ nkb,
    const float* __restrict__ wq, const float* __restrict__ wk,
    const float* __restrict__ wvv, const float* __restrict__ wp,
    ushort* __restrict__ wq_bf, ushort* __restrict__ wk_bf,
    ushort* __restrict__ wv_bf, ushort* __restrict__ wp_bf,
    ushort* __restrict__ q_ln, ushort* __restrict__ kv_ln) {
  __shared__ float preds[2][256];
  __shared__ float pstat[2][32];
  const int bid = blockIdx.x;
  const int tid = threadIdx.x;

  if (bid < 256) {
    // ---- weight fp32 -> bf16 ----
    const int mat = bid >> 6;
    const int base = (bid & 63) * 1024 + tid * 4;
    const float* s; ushort* d;
    switch (mat) {
      case 0: s = wq; d = wq_bf; break;
      case 1: s = wk; d = wk_bf; break;
      case 2: s = wvv; d = wv_bf; break;
      default: s = wp; d = wp_bf; break;
    }
    const float4 v = *reinterpret_cast<const float4*>(s + base);
    uint2 pk;
    pk.x = (uint)f2bf(v.x) | ((uint)f2bf(v.y) << 16);
    pk.y = (uint)f2bf(v.z) | ((uint)f2bf(v.w) << 16);
    *reinterpret_cast<uint2*>(d + base) = pk;
    return;
  }

  if (bid < 768) {
    // ---- LN q: 16 tokens/block, thread = (cg = tid>>4 of 16 ch, tok = tid&15) ----
    const int tok = tid & 15, cg = tid >> 4;
    const int T = (bid - 256) * 16 + tok;         // b*4096 + n
    const int b = T >> 12, n = T & 4095;
    const float* src = q_feat + ((size_t)b * CDIM + cg * 16) * NTOK + n;
    float vals[16];
    float s = 0.f, ss = 0.f;
#pragma unroll
    for (int ci = 0; ci < 16; ++ci) {
      const float v = src[(size_t)ci * NTOK];
      vals[ci] = v;
      s += v; ss = fmaf(v, v, ss);
    }
    preds[0][cg * 16 + tok] = s;
    preds[1][cg * 16 + tok] = ss;
    __syncthreads();
    if (tid < 16) {
      float st = 0.f, sst = 0.f;
#pragma unroll
      for (int k = 0; k < 16; ++k) { st += preds[0][k * 16 + tid]; sst += preds[1][k * 16 + tid]; }
      const float mu = st * (1.f / 256.f);
      const float var = sst * (1.f / 256.f) - mu * mu;
      pstat[0][tid] = mu;
      pstat[1][tid] = rsqrtf(var + LN_EPS);
    }
    __syncthreads();
    const float mu = pstat[0][tok];
    const float rs = pstat[1][tok];
    ushort* dst = q_ln + (size_t)T * CDIM + cg * 16;
#pragma unroll
    for (int ci = 0; ci < 16; ci += 4) {
      ushort h[4];
#pragma unroll
      for (int j = 0; j < 4; ++j) {
        const int c = cg * 16 + ci + j;
        h[j] = f2bf(fmaf((vals[ci + j] - mu) * rs, nqw[c], nqb[c]));
      }
      uint2 pk;
      pk.x = (uint)h[0] | ((uint)h[1] << 16);
      pk.y = (uint)h[2] | ((uint)h[3] << 16);
      *reinterpret_cast<uint2*>(dst + ci) = pk;
    }
    return;
  }

  // ---- pool+LN kv: 8 tokens/block, thread = (cg = tid>>3 of 8 ch, tok = tid&7) ----
  {
    const int tok = tid & 7, cg = tid >> 3;
    const int T = (bid - 768) * 8 + tok;          // b*1024 + nk
    const int b = T >> 10, nk = T & 1023;
    const int hk = nk >> 5, wk2 = nk & 31;
    const float* src = kv_feat + ((size_t)b * CDIM + cg * 8) * NTOK + hk * 128 + wk2 * 2;
    float vals[8];
    float s = 0.f, ss = 0.f;
#pragma unroll
    for (int ci = 0; ci < 8; ++ci) {
      const float* p = src + (size_t)ci * NTOK;
      const float2 r0 = *reinterpret_cast<const float2*>(p);
      const float2 r1 = *reinterpret_cast<const float2*>(p + 64);
      const float v = 0.25f * ((r0.x + r0.y) + (r1.x + r1.y));
      vals[ci] = v;
      s += v; ss = fmaf(v, v, ss);
    }
    preds[0][cg * 8 + tok] = s;
    preds[1][cg * 8 + tok] = ss;
    __syncthreads();
    if (tid < 8) {
      float st = 0.f, sst = 0.f;
#pragma unroll
      for (int k = 0; k < 32; ++k) { st += preds[0][k * 8 + tid]; sst += preds[1][k * 8 + tid]; }
      const float mu = st * (1.f / 256.f);
      const float var = sst * (1.f / 256.f) - mu * mu;
      pstat[0][tid] = mu;
      pstat[1][tid] = rsqrtf(var + LN_EPS);
    }
    __syncthreads();
    const float mu = pstat[0][tok];
    const float rs = pstat[1][tok];
    ushort* dst = kv_ln + (size_t)T * CDIM + cg * 8;
#pragma unroll
    for (int ci = 0; ci < 8; ci += 4) {
      ushort h[4];
#pragma unroll
      for (int j = 0; j < 4; ++j) {
        const int c = cg * 8 + ci + j;
        h[j] = f2bf(fmaf((vals[ci + j] - mu) * rs, nkw[c], nkb[c]));
      }
      uint2 pk;
      pk.x = (uint)h[0] | ((uint)h[1] << 16);
      pk.y = (uint)h[2] | ((uint)h[3] << 16);
      *reinterpret_cast<uint2*>(dst + ci) = pk;
    }
  }
}

// ================= fused QKV projection =================
// blocks: [0,256) Q (M=8192), [256,320) K (M=2048), [320,384) V (M=2048).
// block = 4 waves; wave = 16 rows x 128 cols (rowgrp = wv>>1, colhalf = wv&1).
// K and V are written straight into the attention fragment-tile pack:
//   kvp[bh][kc(8 chunks)][tile(16)][512 ushorts], tile = 1KB, byte-for-byte
//   what attn stages into LDS. Tiles 0..7 = K, 8..15 = V.
//   K: tile t, slot l (=lane), dim-sub jj holds K[key kc*128 + perm(l&15,t)]
//      [dim (l>>4)*8+jj], perm(rr,t) = 32*(t>>1)+8*(rr>>2)+4*(t&1)+(rr&3).
//   V: tile 8+dt*4+ks, slot l holds V[d = dt*16+(l&15)]
//      [key kc*128 + ks*32 + (l>>4)*8 + jj].
__global__ __launch_bounds__(256) void qkv_kernel(
    const ushort* __restrict__ q_ln, const ushort* __restrict__ kv_ln,
    const ushort* __restrict__ wq_bf, const ushort* __restrict__ wk_bf,
    const ushort* __restrict__ wv_bf,
    const float* __restrict__ bq, const float* __restrict__ bk,
    const float* __restrict__ bv,
    ushort* __restrict__ Qp, ushort* __restrict__ kvp) {
  const int bid = blockIdx.x;
  int seg, sb;
  const ushort *X, *W; const float* bias;
  if (bid < 256)      { seg = 0; sb = bid;       X = q_ln;  W = wq_bf; bias = bq; }
  else if (bid < 320) { seg = 1; sb = bid - 256; X = kv_ln; W = wk_bf; bias = bk; }
  else                { seg = 2; sb = bid - 320; X = kv_ln; W = wv_bf; bias = bv; }

  const int lane = threadIdx.x & 63;
  const int wvi = threadIdx.x >> 6;
  const int nlan = lane & 15, g = lane >> 4;
  const int rowgrp = wvi >> 1, colh = wvi & 1;
  const int r0 = sb * 32 + rowgrp * 16;

  f32x4 acc[8];
#pragma unroll
  for (int nt = 0; nt < 8; ++nt) acc[nt] = (f32x4){0.f, 0.f, 0.f, 0.f};

  const ushort* xp = X + (size_t)(r0 + nlan) * CDIM + g * 8;
  const ushort* wp = W + (size_t)(colh * 128 + nlan) * CDIM + g * 8;
#pragma unroll
  for (int k0 = 0; k0 < 8; ++k0) {
    const bf16x8 a = *reinterpret_cast<const bf16x8*>(xp + k0 * 32);
#pragma unroll
    for (int nt = 0; nt < 8; ++nt) {
      const bf16x8 bfr = *reinterpret_cast<const bf16x8*>(wp + (size_t)nt * 16 * CDIM + k0 * 32);
      acc[nt] = __builtin_amdgcn_mfma_f32_16x16x32_bf16(a, bfr, acc[nt], 0, 0, 0);
    }
  }

#pragma unroll
  for (int nt = 0; nt < 8; ++nt) {
    const int j = colh * 128 + nt * 16 + nlan;
    const float bj = bias[j];
#pragma unroll
    for (int reg = 0; reg < 4; ++reg) {
      const int r = r0 + 4 * g + reg;
      const float v = acc[nt][reg] + bj;
      if (seg == 0) {
        Qp[(size_t)r * CDIM + j] = f2bf(v * QSCALE);
      } else if (seg == 1) {
        // K -> pack. r = b*1024 + key, j = h*32 + d.
        const int bb = r >> 10, k = r & 1023;
        const int kc = k >> 7, kk = k & 127;
        const int m = kk >> 5, w = kk & 31;
        const int t = 2 * m + ((w >> 2) & 1);
        const int rr = ((w >> 3) << 2) | (w & 3);
        const int hh = j >> 5, d = j & 31;
        kvp[(((size_t)((bb * 8 + hh) * 8 + kc) * 16 + t) << 9) +
            ((d >> 3) * 16 + rr) * 8 + (d & 7)] = f2bf(v);
      } else {
        // V -> pack. r = b*1024 + key, j = h*32 + d.
        const int bb = r >> 10, mk = r & 1023;
        const int hh = j >> 5, d = j & 31;
        const int dt = d >> 4, rr = d & 15;
        const int kc = mk >> 7, km = mk & 127;
        const int ks = km >> 5, w = km & 31;
        const int gq = w >> 3, jj = w & 7;
        kvp[(((size_t)((bb * 8 + hh) * 8 + kc) * 16 + (8 + dt * 4 + ks)) << 9) +
            (gq * 16 + rr) * 8 + jj] = f2bf(v);
      }
    }
  }
}

// ================= attention =================
// grid (32, 16): x = 128-query tile (4 waves x 32 q), y = b*8+h. 256 threads.
// Per 128-key chunk: 16KB CONTIGUOUS staged via global_load_lds from the
// pre-tiled kvp pack (tile t -> kvf[buf][t], lane l's 16B at +l*16).
// Swapped QK^T: s = mfma_16x16x32(Kfrag, Qfrag) -> D[keyrow][q]; lane holds
// q = lane&15; with the tile permutation, tiles 2m/2m+1 give this lane keys
// 32m+8g+{0..7} -> exp2 + 4x cvt_pk build EXACTLY the 16x16x32 A-fragment
// P[q=nlan][k=8g+j] for PV. No P_lds, no cross-lane ops.
__global__ __launch_bounds__(256) void attn_kernel(const ushort* __restrict__ Qp,
                                                   const ushort* __restrict__ kvp,
                                                   ushort* __restrict__ aout) {
  __shared__ __align__(16) ushort kvf[2][16][512];
  const int lane = threadIdx.x & 63;
  const int wvi = threadIdx.x >> 6;         // 0..3
  const int nlan = lane & 15, g = lane >> 4;
  const int bh = blockIdx.y;
  const int b = bh >> 3, h = bh & 7;
  const int n0 = blockIdx.x * 128 + wvi * 32;

  bf16x8 qf[2];
#pragma unroll
  for (int qt = 0; qt < 2; ++qt)
    qf[qt] = *reinterpret_cast<const bf16x8*>(
        Qp + (size_t)(b * NTOK + n0 + qt * 16 + nlan) * CDIM + h * HDIM + g * 8);

  const ushort* kvb = kvp + ((size_t)bh << 16);   // 8 chunks x 16 tiles x 512

  auto stage = [&](int buf, int kc_idx) {
    const ushort* cb = kvb + ((size_t)kc_idx << 13);
#pragma unroll
    for (int i = 0; i < 4; ++i) {
      const int t = wvi * 4 + i;
      gload_lds16(cb + t * 512 + lane * 8, &kvf[buf][t][0]);
    }
  };

  f32x4 acc[2][2];
#pragma unroll
  for (int qt = 0; qt < 2; ++qt) {
    acc[qt][0] = (f32x4){0.f, 0.f, 0.f, 0.f};
    acc[qt][1] = (f32x4){0.f, 0.f, 0.f, 0.f};
  }
  float lsum[2] = {0.f, 0.f};
  const f32x4 zero = {0.f, 0.f, 0.f, 0.f};

  stage(0, 0);
  for (int c = 0; c < 8; ++c) {
    const int buf = c & 1;
    __syncthreads();                    // chunk c staged & visible
    if (c < 7) stage(buf ^ 1, c + 1);

#pragma unroll
    for (int m = 0; m < 4; ++m) {       // 32-key block
      uint pk[2][4];                    // [qt][4 packed uints = keys 8g+0..7]
#pragma unroll
      for (int half = 0; half < 2; ++half) {
        const bf16x8 kf = *reinterpret_cast<const bf16x8*>(&kvf[buf][2 * m + half][lane * 8]);
#pragma unroll
        for (int qt = 0; qt < 2; ++qt) {
          const f32x4 s = __builtin_amdgcn_mfma_f32_16x16x32_bf16(kf, qf[qt], zero, 0, 0, 0);
          const float p0 = fast_exp2(s[0]), p1 = fast_exp2(s[1]);
          const float p2 = fast_exp2(s[2]), p3 = fast_exp2(s[3]);
          lsum[qt] += (p0 + p1) + (p2 + p3);
          pk[qt][half * 2 + 0] = cvt_pk_bf16(p0, p1);
          pk[qt][half * 2 + 1] = cvt_pk_bf16(p2, p3);
        }
      }
#pragma unroll
      for (int qt = 0; qt < 2; ++qt) {
        const u32x4 w = {pk[qt][0], pk[qt][1], pk[qt][2], pk[qt][3]};
        const bf16x8 af = __builtin_bit_cast(bf16x8, w);
#pragma unroll
        for (int dt = 0; dt < 2; ++dt) {
          const bf16x8 vf = *reinterpret_cast<const bf16x8*>(&kvf[buf][8 + dt * 4 + m][lane * 8]);
          acc[qt][dt] = __builtin_amdgcn_mfma_f32_16x16x32_bf16(af, vf, acc[qt][dt], 0, 0, 0);
        }
      }
    }
  }

  // lsum per lane covers q = nlan, keys {8g..8g+7} over all blocks; reduce over g.
#pragma unroll
  for (int qt = 0; qt < 2; ++qt) {
    lsum[qt] += __shfl_xor(lsum[qt], 16);
    lsum[qt] += __shfl_xor(lsum[qt], 32);
  }

  ushort* dst = aout + (size_t)(b * NTOK + n0) * CDIM + h * HDIM;
#pragma unroll
  for (int qt = 0; qt < 2; ++qt) {
#pragma unroll
    for (int reg = 0; reg < 4; ++reg) {
      // acc row = q-row 4g+reg; its denominator lives at lane 4g+reg (nlan match).
      const float inv = 1.f / __shfl(lsum[qt], 4 * g + reg);
      const size_t row = (size_t)(qt * 16 + 4 * g + reg) * CDIM;
      dst[row + nlan] = f2bf(acc[qt][0][reg] * inv);
      dst[row + 16 + nlan] = f2bf(acc[qt][1][reg] * inv);
    }
  }
}

// ================= out projection + NCHW transpose =================
// 256 blocks x 32 tokens; wave = 16 rows x 128 cols; fp32 out (B,C,N).
__global__ __launch_bounds__(256) void outproj_kernel(const ushort* __restrict__ A,
                                                      const ushort* __restrict__ W,
                                                      const float* __restrict__ bias,
                                                      float* __restrict__ out) {
  __shared__ float ts[256][33];
  const int lane = threadIdx.x & 63;
  const int wvi = threadIdx.x >> 6;
  const int nlan = lane & 15, g = lane >> 4;
  const int rowgrp = wvi >> 1, colh = wvi & 1;
  const int r0b = blockIdx.x * 32;
  const int r0 = r0b + rowgrp * 16;

  f32x4 acc[8];
#pragma unroll
  for (int nt = 0; nt < 8; ++nt) acc[nt] = (f32x4){0.f, 0.f, 0.f, 0.f};

  const ushort* xp = A + (size_t)(r0 + nlan) * CDIM + g * 8;
  const ushort* wp = W + (size_t)(colh * 128 + nlan) * CDIM + g * 8;
#pragma unroll
  for (int k0 = 0; k0 < 8; ++k0) {
    const bf16x8 a = *reinterpret_cast<const bf16x8*>(xp + k0 * 32);
#pragma unroll
    for (int nt = 0; nt < 8; ++nt) {
      const bf16x8 bfr = *reinterpret_cast<const bf16x8*>(wp + (size_t)nt * 16 * CDIM + k0 * 32);
      acc[nt] = __builtin_amdgcn_mfma_f32_16x16x32_bf16(a, bfr, acc[nt], 0, 0, 0);
    }
  }

#pragma unroll
  for (int nt = 0; nt < 8; ++nt) {
    const int j = colh * 128 + nt * 16 + nlan;
    const float bj = bias[j];
#pragma unroll
    for (int reg = 0; reg < 4; ++reg)
      ts[j][rowgrp * 16 + 4 * g + reg] = acc[nt][reg] + bj;
  }
  __syncthreads();
  const int b = r0b >> 12;
  const int n0g = r0b & 4095;
#pragma unroll
  for (int k = 0; k < 32; ++k) {
    const int idx = k * 256 + threadIdx.x;
    const int cl = idx >> 5, tok = idx & 31;
    out[((size_t)b * CDIM + cl) * NTOK + n0g + tok] = ts[cl][tok];
  }
}

extern "C" void kernel_launch(void* const* d_in, const int* in_sizes, int n_in,
                              void* d_out, int out_size, void* d_ws, size_t ws_size,
                              hipStream_t stream) {
  (void)in_sizes; (void)n_in; (void)out_size; (void)ws_size;
  const float* q_feat  = (const float*)d_in[0];
  const float* kv_feat = (const float*)d_in[1];
  const float* nqw = (const float*)d_in[2];
  const float* nqb = (const float*)d_in[3];
  const float* nkw = (const float*)d_in[4];
  const float* nkb = (const float*)d_in[5];
  const float* wq  = (const float*)d_in[6];
  const float* bq  = (const float*)d_in[7];
  const float* wk  = (const float*)d_in[8];
  const float* bk  = (const float*)d_in[9];
  const float* wv  = (const float*)d_in[10];
  const float* bv  = (const float*)d_in[11];
  const float* wp  = (const float*)d_in[12];
  const float* bp  = (const float*)d_in[13];
  float* out = (float*)d_out;

  ushort* p = (ushort*)d_ws;
  ushort* wq_bf = p; p += 65536;
  ushort* wk_bf = p; p += 65536;
  ushort* wv_bf = p; p += 65536;
  ushort* wp_bf = p; p += 65536;
  ushort* q_ln  = p; p += 8192 * 256;
  ushort* kv_ln = p; p += 2048 * 256;
  ushort* Qp    = p; p += 8192 * 256;
  ushort* kvp   = p; p += 16 * 8 * 16 * 512;   // [bh][kc][tile][512] = 2MB
  ushort* aout  = p; p += 8192 * 256;

  prep_kernel<<<1024, 256, 0, stream>>>(q_feat, kv_feat, nqw, nqb, nkw, nkb,
                                        wq, wk, wv, wp,
                                        wq_bf, wk_bf, wv_bf, wp_bf, q_ln, kv_ln);
  qkv_kernel<<<384, 256, 0, stream>>>(q_ln, kv_ln, wq_bf, wk_bf, wv_bf,
                                      bq, bk, bv, Qp, kvp);
  attn_kernel<<<dim3(32, 16), 256, 0, stream>>>(Qp, kvp, aout);
  outproj_kernel<<<256, 256, 0, stream>>>(aout, wp_bf, bp, out);
}